// Round 2
// baseline (946.597 us; speedup 1.0000x reference)
//
#include <hip/hip_runtime.h>
#include <math.h>

// Problem constants (from reference):
//   N = 500000 nodes, C = 256 channels, B = 1024 segments, hidden = C/R = 64
#define CCH   256
#define CCH4  64        // C / 4 (float4 groups per row)
#define BSEG  1024
#define HID   64
#define RPW   64        // rows per wave in seg_reduce

// Monotonic float->uint encode for atomicMax on floats.
// encode is strictly increasing; all real floats encode > 0, so key==0 means
// "never written" (empty segment) -> decode to 0 per torch_scatter fill.
__device__ __forceinline__ unsigned enc_f32(float f) {
  unsigned u = __float_as_uint(f);
  return (u & 0x80000000u) ? ~u : (u | 0x80000000u);
}
__device__ __forceinline__ float dec_f32(unsigned u) {
  return (u & 0x80000000u) ? __uint_as_float(u & 0x7fffffffu)
                           : __uint_as_float(~u);
}

// ---------------------------------------------------------------------------
// Kernel 1: segment sum+max via row-chunked atomics. batch is sorted.
// Each wave owns 64 consecutive rows; reads its 64 batch ids in ONE coalesced
// load; register-accumulates float4 per lane; flushes partials with
// atomicAdd / atomicMax(encoded). 7813 waves -> ~30 waves/CU (full occupancy)
// of independent streaming float4 loads.
// ---------------------------------------------------------------------------
__global__ __launch_bounds__(256) void seg_reduce_kernel(
    const float* __restrict__ x, const int* __restrict__ batch, int N,
    float* __restrict__ sum_res, unsigned* __restrict__ max_keys) {
  int wave = (blockIdx.x << 2) | (threadIdx.x >> 6);
  int lane = threadIdx.x & 63;
  int start = wave * RPW;
  if (start >= N) return;
  int cnt = min(RPW, N - start);

  // one coalesced load of this chunk's batch ids
  int bv = batch[min(start + lane, N - 1)];
  int b_first = __shfl(bv, 0);
  int b_last  = __shfl(bv, cnt - 1);

  const float4* x4 = (const float4*)x;
  const float4* xp = x4 + (size_t)start * CCH4 + lane;

  float4 s = make_float4(0.f, 0.f, 0.f, 0.f);
  float4 m = make_float4(-INFINITY, -INFINITY, -INFINITY, -INFINITY);

  auto flush = [&](int seg) {
    float* sp = sum_res + (size_t)seg * CCH + (lane << 2);
    unsigned* mp = max_keys + (size_t)seg * CCH + (lane << 2);
    atomicAdd(sp + 0, s.x); atomicAdd(sp + 1, s.y);
    atomicAdd(sp + 2, s.z); atomicAdd(sp + 3, s.w);
    atomicMax(mp + 0, enc_f32(m.x)); atomicMax(mp + 1, enc_f32(m.y));
    atomicMax(mp + 2, enc_f32(m.z)); atomicMax(mp + 3, enc_f32(m.w));
  };

  if (b_first == b_last && cnt == RPW) {
    // fast path (~87% of waves): whole chunk in one segment, fixed trip count
    #pragma unroll 8
    for (int r = 0; r < RPW; ++r) {
      float4 v = xp[(size_t)r * CCH4];
      s.x += v.x; s.y += v.y; s.z += v.z; s.w += v.w;
      m.x = fmaxf(m.x, v.x); m.y = fmaxf(m.y, v.y);
      m.z = fmaxf(m.z, v.z); m.w = fmaxf(m.w, v.w);
    }
    flush(b_first);
  } else {
    int cur = b_first;
    for (int r = 0; r < cnt; ++r) {
      int b = __shfl(bv, r);
      if (b != cur) {  // wave-uniform branch, rare
        flush(cur);
        cur = b;
        s = make_float4(0.f, 0.f, 0.f, 0.f);
        m = make_float4(-INFINITY, -INFINITY, -INFINITY, -INFINITY);
      }
      float4 v = xp[(size_t)r * CCH4];
      s.x += v.x; s.y += v.y; s.z += v.z; s.w += v.w;
      m.x = fmaxf(m.x, v.x); m.y = fmaxf(m.y, v.y);
      m.z = fmaxf(m.z, v.z); m.w = fmaxf(m.w, v.w);
    }
    flush(cur);
  }
}

// ---------------------------------------------------------------------------
// Kernel 2: y = relu(mlp(max) + mlp(sum)) per segment, exploiting linearity
// of the second matmul: y[c] = relu( sum_j (hs[j]+hm[j]) * w2[j][c] ).
// Decodes max keys (key==0 -> empty segment -> 0).
// ---------------------------------------------------------------------------
__global__ __launch_bounds__(256) void mlp_kernel(
    const float* __restrict__ sum_res, const unsigned* __restrict__ max_keys,
    const float* __restrict__ w1, const float* __restrict__ w2,
    float* __restrict__ y) {
  int seg = blockIdx.x;
  int t = threadIdx.x;
  __shared__ float srow[CCH];
  __shared__ float mrow[CCH];
  __shared__ float hsum[HID];
  __shared__ float hmax[HID];

  srow[t] = sum_res[(size_t)seg * CCH + t];
  unsigned key = max_keys[(size_t)seg * CCH + t];
  mrow[t] = (key == 0u) ? 0.f : dec_f32(key);
  __syncthreads();

  if (t < HID) {
    float acc = 0.f;
    #pragma unroll 8
    for (int k = 0; k < CCH; ++k) acc = fmaf(srow[k], w1[k * HID + t], acc);
    hsum[t] = fmaxf(acc, 0.f);
  } else if (t < 2 * HID) {
    int j = t - HID;
    float acc = 0.f;
    #pragma unroll 8
    for (int k = 0; k < CCH; ++k) acc = fmaf(mrow[k], w1[k * HID + j], acc);
    hmax[j] = fmaxf(acc, 0.f);
  }
  __syncthreads();

  float acc = 0.f;
  #pragma unroll 8
  for (int j = 0; j < HID; ++j) acc = fmaf(hsum[j] + hmax[j], w2[j * CCH + t], acc);
  y[(size_t)seg * CCH + t] = fmaxf(acc, 0.f);
}

// ---------------------------------------------------------------------------
// Kernel 3: out[n][c] = x[n][c] * y[batch[n]][c], vectorized float4.
// All 64 lanes of a wave share one node n -> batch[n] broadcast; y (1 MB) is
// L2-resident; x/out stream at copy BW.
// ---------------------------------------------------------------------------
__global__ __launch_bounds__(256) void gate_kernel(
    const float* __restrict__ x, const int* __restrict__ batch,
    const float* __restrict__ y, float* __restrict__ out, int total4) {
  int idx = blockIdx.x * blockDim.x + threadIdx.x;
  if (idx >= total4) return;
  int n = idx >> 6;        // node
  int q = idx & 63;        // float4 group within row
  int b = batch[n];
  const float4* x4 = (const float4*)x;
  const float4* y4 = (const float4*)y;
  float4 xv = x4[idx];
  float4 yv = y4[b * CCH4 + q];
  float4 o;
  o.x = xv.x * yv.x; o.y = xv.y * yv.y; o.z = xv.z * yv.z; o.w = xv.w * yv.w;
  ((float4*)out)[idx] = o;
}

extern "C" void kernel_launch(void* const* d_in, const int* in_sizes, int n_in,
                              void* d_out, int out_size, void* d_ws, size_t ws_size,
                              hipStream_t stream) {
  const float* x     = (const float*)d_in[0];   // [N, C]
  const int*   batch = (const int*)d_in[1];     // [N]
  const float* w1    = (const float*)d_in[2];   // [C, 64]
  const float* w2    = (const float*)d_in[3];   // [64, C]
  float* out = (float*)d_out;                   // [N, C]

  int N = in_sizes[1];                          // 500000

  // Workspace: sum_res [B*C] f32 | max_keys [B*C] u32 | y [B*C] f32
  float*    sum_res  = (float*)d_ws;
  unsigned* max_keys = (unsigned*)(sum_res + (size_t)BSEG * CCH);
  float*    y        = (float*)(max_keys + (size_t)BSEG * CCH);

  // zero-init sum + max-key buffers (2 MB); graph-capturable async memset
  hipMemsetAsync(d_ws, 0, (size_t)2 * BSEG * CCH * sizeof(float), stream);

  int waves  = (N + RPW - 1) / RPW;             // 7813
  int blocks = (waves + 3) / 4;                 // 4 waves per 256-thread block
  seg_reduce_kernel<<<blocks, 256, 0, stream>>>(x, batch, N, sum_res, max_keys);
  mlp_kernel<<<BSEG, 256, 0, stream>>>(sum_res, max_keys, w1, w2, y);

  int total4 = N * CCH4;                        // N*C/4 = 32,000,000
  int gblocks = (total4 + 255) / 256;
  gate_kernel<<<gblocks, 256, 0, stream>>>(x, batch, y, out, total4);
}